// Round 4
// baseline (96.902 us; speedup 1.0000x reference)
//
#include <hip/hip_runtime.h>

// MonotoneActivation: B=4096, G=512, K=4, D=8
// out[b, g*8+d] = sum_j coef_j * params[g, idx_j, d]
// Round 4: one thread per (b,g) (sort computed once), G_TILE=64 so each
// wave's X load / output stores cover one dense contiguous row segment,
// and all 8 X values prefetched into registers (8 loads in flight) before
// the unrolled compute loop — attack latency serialization, not density.

#define BB 4096
#define GG 512
#define G_TILE 64
#define NB 8            // b-iterations; block = 64 g x 4 b per iter -> 32 b
#define G_STRIDE 33     // float4 per g in LDS (32 + 1 pad)

__global__ __launch_bounds__(256) void monoact_kernel(
    const float4* __restrict__ X4,   // (B, 512) float4 view of X (B, 2048) fp32
    const float4* __restrict__ P4,   // (G, 32) float4 view of params (G,16,8) fp32
    float4* __restrict__ O4)         // (B, 1024) float4 view of out (B, 4096) fp32
{
    __shared__ float4 lds_p[G_TILE * G_STRIDE];   // 33792 B

    const int tid = threadIdx.x;
    const int g0 = blockIdx.x * G_TILE;
    const int b0 = blockIdx.y * (4 * NB);

    // Stage params[g0..g0+63] (2048 float4, 32 KB) into LDS, padded layout.
#pragma unroll
    for (int k = 0; k < 8; ++k) {
        const int j = tid + k * 256;
        const int g_l = j >> 5;
        const int rem = j & 31;
        lds_p[g_l * G_STRIDE + rem] = P4[(size_t)(g0 + g_l) * 32 + rem];
    }
    __syncthreads();

    const int g_l = tid & (G_TILE - 1);
    const int b_l = tid >> 6;            // 0..3
    const int g = g0 + g_l;
    const float4* __restrict__ pg = lds_p + g_l * G_STRIDE;

    // Prefetch all NB X values: 8 independent 1 KiB-dense wave loads in flight.
    float4 xs[NB];
#pragma unroll
    for (int it = 0; it < NB; ++it) {
        const int b = b0 + it * 4 + b_l;
        xs[it] = X4[(size_t)b * 512 + g];
    }

#pragma unroll
    for (int it = 0; it < NB; ++it) {
        const int b = b0 + it * 4 + b_l;
        const float4 x = xs[it];

        float v[4] = {x.x, x.y, x.z, x.w};
        int   id[4] = {0, 1, 2, 3};
#define CSWAP(a, c)                                               \
        {                                                         \
            bool sw = v[a] > v[c];                                \
            float tv = sw ? v[a] : v[c];                          \
            v[a] = sw ? v[c] : v[a];                              \
            v[c] = tv;                                            \
            int ti = sw ? id[a] : id[c];                          \
            id[a] = sw ? id[c] : id[a];                           \
            id[c] = ti;                                           \
        }
        CSWAP(0, 1)
        CSWAP(2, 3)
        CSWAP(0, 2)
        CSWAP(1, 3)
        CSWAP(1, 2)
#undef CSWAP

        const float c0 = v[0];
        const float c1 = v[1] - v[0];
        const float c2 = v[2] - v[1];
        const float c3 = v[3] - v[2];

        const int r0 = 15;
        const int r1 = r0 - (1 << id[0]);
        const int r2 = r1 - (1 << id[1]);
        const int r3 = r2 - (1 << id[2]);

        const float4 a0 = pg[r0 * 2],     a0h = pg[r0 * 2 + 1];
        const float4 a1 = pg[r1 * 2],     a1h = pg[r1 * 2 + 1];
        const float4 a2 = pg[r2 * 2],     a2h = pg[r2 * 2 + 1];
        const float4 a3 = pg[r3 * 2],     a3h = pg[r3 * 2 + 1];

        float4 o0, o1;
        o0.x = fmaf(c0, a0.x, fmaf(c1, a1.x, fmaf(c2, a2.x, c3 * a3.x)));
        o0.y = fmaf(c0, a0.y, fmaf(c1, a1.y, fmaf(c2, a2.y, c3 * a3.y)));
        o0.z = fmaf(c0, a0.z, fmaf(c1, a1.z, fmaf(c2, a2.z, c3 * a3.z)));
        o0.w = fmaf(c0, a0.w, fmaf(c1, a1.w, fmaf(c2, a2.w, c3 * a3.w)));
        o1.x = fmaf(c0, a0h.x, fmaf(c1, a1h.x, fmaf(c2, a2h.x, c3 * a3h.x)));
        o1.y = fmaf(c0, a0h.y, fmaf(c1, a1h.y, fmaf(c2, a2h.y, c3 * a3h.y)));
        o1.z = fmaf(c0, a0h.z, fmaf(c1, a1h.z, fmaf(c2, a2h.z, c3 * a3h.z)));
        o1.w = fmaf(c0, a0h.w, fmaf(c1, a1h.w, fmaf(c2, a2h.w, c3 * a3h.w)));

        // Wave covers one b-row, 64 consecutive g: 2 stores fill a dense 2 KiB span.
        float4* __restrict__ o = O4 + (size_t)b * 1024 + (size_t)g * 2;
        o[0] = o0;
        o[1] = o1;
    }
}

extern "C" void kernel_launch(void* const* d_in, const int* in_sizes, int n_in,
                              void* d_out, int out_size, void* d_ws, size_t ws_size,
                              hipStream_t stream) {
    const float4* X4 = (const float4*)d_in[0];   // X: (4096, 2048) fp32
    const float4* P4 = (const float4*)d_in[1];   // params: (512, 16, 8) fp32
    float4* O4 = (float4*)d_out;                 // out: (4096, 4096) fp32

    dim3 grid(GG / G_TILE, BB / (4 * NB));       // (8, 128) = 1024 blocks
    monoact_kernel<<<grid, 256, 0, stream>>>(X4, P4, O4);
}